// Round 18
// baseline (515.714 us; speedup 1.0000x reference)
//
#include <hip/hip_runtime.h>
#include <stdint.h>

// HeadwiseLowRankModule: out = blockdiag-GEMM(GEMM(hidden, VT^T), U^T), f32 I/O.
// ROUND 18: r17 + T4 counted-vmcnt pipeline in GEMM1:
//  - A: 2-deep register banks (pa/pb), loaded 2 tiles ahead (full-tile shadow)
//  - B: gload issue moved into the cvt window (full-tile shadow)
//  - barrier_A = lgkmcnt(0)-only s_barrier (no vmem drain)
//  - barrier_B = vmcnt(12)+lgkmcnt(0) s_barrier (retires exactly B(kt))
//  Queue invariant at barrier_A(kt): [bank(kt)x8, B(kt)x4, bank(kt+1)x8];
//  in-order vmcnt retirement (m135). Tail: last body WB=0.
// GEMM2: + T2 swizzle (same 16-way conflict fix as r17's GEMM1).

typedef short  bf16x8  __attribute__((ext_vector_type(8)));
typedef float  f32x4   __attribute__((ext_vector_type(4)));
typedef ushort ushort8 __attribute__((ext_vector_type(8)));
typedef float  flt4    __attribute__((ext_vector_type(4)));

__device__ __forceinline__ void gload_lds16(const ushort* g, ushort* l) {
    __builtin_amdgcn_global_load_lds(
        (const __attribute__((address_space(1))) uint32_t*)g,
        (__attribute__((address_space(3))) uint32_t*)l, 16, 0, 0);
}

__device__ __forceinline__ ushort f2bf(float f) {
    union { float f; uint32_t u; } c; c.f = f;
    uint32_t u = c.u;
    uint32_t r = (u + 0x7FFFu + ((u >> 16) & 1u)) >> 16;  // RNE
    return (ushort)r;
}

__device__ __forceinline__ uint32_t cvtpk(float lo, float hi) {
    uint32_t r;
    asm("v_cvt_pk_bf16_f32 %0, %1, %2" : "=v"(r) : "v"(lo), "v"(hi));
    return r;
}

// ---- f32 -> bf16 conversion for VT + U only ----
__device__ __forceinline__ void conv_seg(const float* __restrict__ in,
                                         ushort* __restrict__ out,
                                         long n8, int bid, int nblk) {
    const long stride = (long)nblk * 256;
    for (long i = (long)bid * 256 + threadIdx.x; i < n8; i += stride) {
        flt4 a = ((const flt4*)in)[2 * i];
        flt4 b = ((const flt4*)in)[2 * i + 1];
        ushort8 o;
        o[0] = f2bf(a[0]); o[1] = f2bf(a[1]); o[2] = f2bf(a[2]); o[3] = f2bf(a[3]);
        o[4] = f2bf(b[0]); o[5] = f2bf(b[1]); o[6] = f2bf(b[2]); o[7] = f2bf(b[3]);
        ((ushort8*)out)[i] = o;
    }
}

__global__ __launch_bounds__(256) void convert_vt_u_kernel(
    const float* __restrict__ vt_f, ushort* __restrict__ vt_b, long nVT8,
    const float* __restrict__ u_f,  ushort* __restrict__ u_b,  long nU8)
{
    const int b = blockIdx.x;
    if (b < 896) conv_seg(vt_f, vt_b, nVT8, b,       896);
    else         conv_seg(u_f,  u_b,  nU8,  b - 896, 128);
}

// ---- store helpers ----
__device__ __forceinline__ void store_out(ushort* p, float v) { *p = f2bf(v); }
__device__ __forceinline__ void store_out(float*  p, float v) { *p = v; }

// =====================================================================
// GEMM1: latent[16384 x 2048] = hidden_f32[16384 x 4096] * VT_bf16^T
// 4-wave 128x128, T2 swizzle, 2-deep A banks, counted-vmcnt barriers.
// =====================================================================

// one K-tile body. BANK = pa or pb (bank for tile KT and reload for KT+2).
#define G1_BODY(BANK, KT, ISSB, ISSA, WB) do { \
    /* barrier_A: LDS ordering only (no vmem drain) */ \
    asm volatile("s_waitcnt lgkmcnt(0)" ::: "memory"); \
    __builtin_amdgcn_s_barrier(); \
    /* cvt + ds_write A(KT) from BANK (compiler waits vmcnt for BANK only) */ \
    _Pragma("unroll") \
    for (int i = 0; i < 4; ++i) { \
        uint4 w_; \
        w_.x = cvtpk(BANK[2*i][0],   BANK[2*i][1]); \
        w_.y = cvtpk(BANK[2*i][2],   BANK[2*i][3]); \
        w_.z = cvtpk(BANK[2*i+1][0], BANK[2*i+1][1]); \
        w_.w = cvtpk(BANK[2*i+1][2], BANK[2*i+1][3]); \
        *(uint4*)(aDstBase + i * 512) = w_; \
    } \
    /* window: issue B(KT+1) -> Bs[other] (its readers done before barrier_A) */ \
    if (ISSB) { \
        _Pragma("unroll") \
        for (int i = 0; i < 4; ++i) \
            gload_lds16(bPtr + (size_t)i * 8 * ldb + ((KT) + 1) * 64, \
                        Bs[((KT) + 1) & 1] + (wave * 4 + i) * 512); \
    } \
    /* barrier_B: retire exactly B(KT) (oldest), keep A banks in flight */ \
    asm volatile("s_waitcnt vmcnt(" #WB ") lgkmcnt(0)" ::: "memory"); \
    __builtin_amdgcn_s_barrier(); \
    /* reload BANK with A(KT+2) (regs just freed by cvt) */ \
    if (ISSA) { \
        _Pragma("unroll") \
        for (int i = 0; i < 4; ++i) { \
            const float* s_ = aF + (size_t)(i * 8) * lda + ((KT) + 2) * 64; \
            BANK[2*i]   = *(const flt4*)(s_); \
            BANK[2*i+1] = *(const flt4*)(s_ + 4); \
        } \
    } \
    /* MFMA tile KT */ \
    { \
        const ushort* bCur = Bs[(KT) & 1]; \
        _Pragma("unroll") \
        for (int kk = 0; kk < 2; ++kk) { \
            const int rc = ((((kk << 2) | lq) ^ l7) << 3); \
            bf16x8 af[4], bfr[4]; \
            _Pragma("unroll") \
            for (int m = 0; m < 4; ++m) \
                af[m] = *(const bf16x8*)&As[(wr * 64 + m * 16 + l15) * 64 + rc]; \
            _Pragma("unroll") \
            for (int n = 0; n < 4; ++n) \
                bfr[n] = *(const bf16x8*)&bCur[(wc * 64 + n * 16 + l15) * 64 + rc]; \
            _Pragma("unroll") \
            for (int m = 0; m < 4; ++m) \
                _Pragma("unroll") \
                for (int n = 0; n < 4; ++n) \
                    acc[m][n] = __builtin_amdgcn_mfma_f32_16x16x32_bf16( \
                        af[m], bfr[n], acc[m][n], 0, 0, 0); \
        } \
    } \
} while (0)

__global__ __launch_bounds__(256) void gemm1_fused_kernel(
    const float* __restrict__ Af,
    const ushort* __restrict__ B,
    ushort* __restrict__ C,
    int lda, int ldb, int ldc, int K, int bxShift)
{
    __shared__ ushort As[128 * 64];      // 16 KiB (single, swizzled)
    __shared__ ushort Bs[2][128 * 64];   // 32 KiB (double, swizzled via src)

    const int tid  = threadIdx.x;
    const int lane = tid & 63;
    const int wave = tid >> 6;

    const int bid = blockIdx.x;
    const int xcd = bid & 7;
    const int rr  = bid >> 3;
    const int by  = xcd * 16 + (rr >> bxShift);
    const int bx  = rr & ((1 << bxShift) - 1);

    const int row0 = by * 128;
    const int col0 = bx * 128;

    const int wr = wave >> 1;
    const int wc = wave & 1;

    const int l15    = lane & 15;
    const int lq     = lane >> 4;
    const int lrow   = lane >> 3;
    const int lchunk = lane & 7;
    const int l7     = lane & 7;

    f32x4 acc[4][4] = {};
    flt4 pa[8], pb[8];               // two A banks (64 VGPR)

    const float*  aF   = Af + (size_t)(row0 + wave * 32 + lrow) * lda + lchunk * 8;
    const ushort* bPtr = B  + (size_t)(col0 + wave * 32 + lrow) * ldb
                            + ((lchunk ^ lrow) * 8);
    ushort* aDstBase = As + wave * 4 * 512 + lrow * 64 + ((lchunk ^ lrow) * 8);

    const int nkt = K / 64;          // 64 (even)

    // Prologue establishes queue invariant [bank(0)x8, B(0)x4, bank(1)x8]
    #pragma unroll
    for (int i = 0; i < 4; ++i) {
        const float* s = aF + (size_t)(i * 8) * lda;
        pa[2*i] = *(const flt4*)(s);  pa[2*i+1] = *(const flt4*)(s + 4);
    }
    #pragma unroll
    for (int i = 0; i < 4; ++i)
        gload_lds16(bPtr + (size_t)i * 8 * ldb, Bs[0] + (wave * 4 + i) * 512);
    #pragma unroll
    for (int i = 0; i < 4; ++i) {
        const float* s = aF + (size_t)(i * 8) * lda + 64;
        pb[2*i] = *(const flt4*)(s);  pb[2*i+1] = *(const flt4*)(s + 4);
    }

    // main pairs: bodies 0..nkt-3 (all issues unguarded-safe)
    for (int kt = 0; kt + 2 < nkt; kt += 2) {
        G1_BODY(pa, kt,     1, 1, 12);
        G1_BODY(pb, kt + 1, 1, 1, 12);
    }
    // peeled tail: body nkt-2 (no A reload), body nkt-1 (no issues, drain)
    {
        const int kt = nkt - 2;
        G1_BODY(pa, kt,     1, 0, 12);
        G1_BODY(pb, kt + 1, 0, 0, 0);
    }

    // C/D layout: col = lane&15, row = (lane>>4)*4 + reg
    #pragma unroll
    for (int m = 0; m < 4; ++m) {
        #pragma unroll
        for (int r = 0; r < 4; ++r) {
            const size_t row = (size_t)(row0 + wr * 64 + m * 16 + lq * 4 + r);
            ushort* cRow = C + row * ldc + col0 + wc * 64 + l15;
            #pragma unroll
            for (int n = 0; n < 4; ++n)
                cRow[n * 16] = f2bf(acc[m][n][r]);
        }
    }
}

// =====================================================================
// GEMM2 (8-wave) + T2 swizzle: block-diagonal
// out[:, g*512:+512] = latent[:, g*256:+256] * U[g]^T, f32 out.
// Swizzle invariant: LDS[r][chunk] = global[r][chunk ^ (r&7)].
// =====================================================================
template <typename TOUT>
__global__ __launch_bounds__(512) void gemm_bt8_kernel(
    const ushort* __restrict__ A,
    const ushort* __restrict__ B,
    TOUT* __restrict__ C,
    int lda, int ldb, int ldc, int K, int bxShift,
    long aOffZ, long bOffZ, long cOffZ)
{
    A += (size_t)blockIdx.z * aOffZ;
    B += (size_t)blockIdx.z * bOffZ;
    C += (size_t)blockIdx.z * cOffZ;

    __shared__ ushort As[128 * 64];
    __shared__ ushort Bs[128 * 64];

    const int tid  = threadIdx.x;
    const int lane = tid & 63;
    const int wave = tid >> 6;       // 0..7

    const int bid = blockIdx.x;
    const int xcd = bid & 7;
    const int rr  = bid >> 3;
    const int by  = xcd * 16 + (rr >> bxShift);
    const int bx  = rr & ((1 << bxShift) - 1);

    const int row0 = by * 128;
    const int col0 = bx * 128;

    const int wr = wave >> 2;        // 0..1
    const int wc = wave & 3;         // 0..3

    const int l15    = lane & 15;
    const int lq     = lane >> 4;
    const int lrow   = lane >> 3;
    const int lchunk = lane & 7;
    const int l7     = lane & 7;

    f32x4 acc[4][2] = {};

    // pre-swizzled global sources (chunk ^ lrow); staging rows have r&7==lrow
    const ushort* aPtr = A + (size_t)(row0 + wave * 8 + lrow) * lda
                           + ((lchunk ^ lrow) * 8);
    const ushort* bPtr = B + (size_t)(col0 + wave * 8 + lrow) * ldb
                           + ((lchunk ^ lrow) * 8);
    const int ldsseg = wave * 512;

    const int nkt = K / 64;
    for (int kt = 0; kt < nkt; ++kt) {
        const int kOff = kt * 64;
        __syncthreads();
        #pragma unroll
        for (int i = 0; i < 2; ++i) {
            gload_lds16(aPtr + (size_t)i * 64 * lda + kOff, As + i * 4096 + ldsseg);
            gload_lds16(bPtr + (size_t)i * 64 * ldb + kOff, Bs + i * 4096 + ldsseg);
        }
        __syncthreads();

        #pragma unroll
        for (int kk = 0; kk < 2; ++kk) {
            const int rc = ((((kk << 2) | lq) ^ l7) << 3);
            bf16x8 af[4], bfr[2];
            #pragma unroll
            for (int m = 0; m < 4; ++m)
                af[m] = *(const bf16x8*)&As[(wr * 64 + m * 16 + l15) * 64 + rc];
            #pragma unroll
            for (int n = 0; n < 2; ++n)
                bfr[n] = *(const bf16x8*)&Bs[(wc * 32 + n * 16 + l15) * 64 + rc];
            #pragma unroll
            for (int m = 0; m < 4; ++m)
                #pragma unroll
                for (int n = 0; n < 2; ++n)
                    acc[m][n] = __builtin_amdgcn_mfma_f32_16x16x32_bf16(
                        af[m], bfr[n], acc[m][n], 0, 0, 0);
        }
    }

    #pragma unroll
    for (int m = 0; m < 4; ++m) {
        #pragma unroll
        for (int r = 0; r < 4; ++r) {
            const size_t row = (size_t)(row0 + wr * 64 + m * 16 + lq * 4 + r);
            TOUT* cRow = C + row * ldc + col0 + wc * 32 + l15;
            #pragma unroll
            for (int n = 0; n < 2; ++n)
                store_out(cRow + n * 16, acc[m][n][r]);
        }
    }
}

extern "C" void kernel_launch(void* const* d_in, const int* in_sizes, int n_in,
                              void* d_out, int out_size, void* d_ws, size_t ws_size,
                              hipStream_t stream) {
    const float* hidden_f = (const float*)d_in[0];  // 16384 x 4096 f32
    const float* VT_f     = (const float*)d_in[1];  // 2048 x 4096 f32 (N,K)
    const float* U_f      = (const float*)d_in[2];  // 8 x 512 x 256 f32
    float* out = (float*)d_out;                     // 16384 x 4096 f32

    const long nVT  = 2048L * 4096L;
    const long nU   = 8L * 512L * 256L;
    const long nLat = 16384L * 2048L;

    // lat_b and u_b MUST live in ws (GEMM2 reads them while writing d_out).
    // vt_b may fall back into d_out (read only by GEMM1, which writes ws).
    ushort *vt_b, *u_b, *lat_b;
    const size_t needA = (size_t)(nVT + nU + nLat) * 2;   // ~86 MB
    ushort* w = (ushort*)d_ws;
    lat_b = w;  u_b = lat_b + nLat;
    if (ws_size >= needA) vt_b = u_b + nU;
    else                  vt_b = (ushort*)d_out;          // staged in d_out

    // convert VT + U (~100 MB traffic)
    convert_vt_u_kernel<<<dim3(1024), dim3(256), 0, stream>>>(
        VT_f, vt_b, nVT / 8, U_f, u_b, nU / 8);

    // GEMM1: latent = hidden_f32 * VT^T (fused, T2 swizzle, counted vmcnt)
    gemm1_fused_kernel<<<dim3(2048, 1, 1), dim3(256), 0, stream>>>(
        hidden_f, vt_b, lat_b, 4096, 4096, 2048, 4096, 4);

    // GEMM2 (block-diag, 8-wave, T2 swizzle)
    gemm_bt8_kernel<float><<<dim3(512, 1, 8), dim3(512), 0, stream>>>(
        lat_b, u_b, out, 2048, 256, 4096, 256, 2,
        256L, 512L * 256L, 512L);
}

// Round 19
// 461.108 us; speedup vs baseline: 1.1184x; 1.1184x over previous
//
#include <hip/hip_runtime.h>
#include <stdint.h>

// HeadwiseLowRankModule: out = blockdiag-GEMM(GEMM(hidden, VT^T), U^T), f32 I/O.
// ROUND 19: r18's A-bank pipeline REVERTED (VGPR 120 -> occupancy 22, -16%).
// GEMM1 = r17 single-bank structure + zero-cost shadow extension:
//   B(kt+1) issued inside the cvt window; barrier_B = raw lgkmcnt(0)-only
//   s_barrier (B stays in flight across it; retired at next barrier_A's
//   full __syncthreads drain). pa reload right after cvt (WAR keeps order).
// GEMM2 = r18's T2-swizzled 8-wave kernel verbatim (passed).

typedef short  bf16x8  __attribute__((ext_vector_type(8)));
typedef float  f32x4   __attribute__((ext_vector_type(4)));
typedef ushort ushort8 __attribute__((ext_vector_type(8)));
typedef float  flt4    __attribute__((ext_vector_type(4)));

__device__ __forceinline__ void gload_lds16(const ushort* g, ushort* l) {
    __builtin_amdgcn_global_load_lds(
        (const __attribute__((address_space(1))) uint32_t*)g,
        (__attribute__((address_space(3))) uint32_t*)l, 16, 0, 0);
}

__device__ __forceinline__ ushort f2bf(float f) {
    union { float f; uint32_t u; } c; c.f = f;
    uint32_t u = c.u;
    uint32_t r = (u + 0x7FFFu + ((u >> 16) & 1u)) >> 16;  // RNE
    return (ushort)r;
}

__device__ __forceinline__ uint32_t cvtpk(float lo, float hi) {
    uint32_t r;
    asm("v_cvt_pk_bf16_f32 %0, %1, %2" : "=v"(r) : "v"(lo), "v"(hi));
    return r;
}

// ---- f32 -> bf16 conversion for VT + U only ----
__device__ __forceinline__ void conv_seg(const float* __restrict__ in,
                                         ushort* __restrict__ out,
                                         long n8, int bid, int nblk) {
    const long stride = (long)nblk * 256;
    for (long i = (long)bid * 256 + threadIdx.x; i < n8; i += stride) {
        flt4 a = ((const flt4*)in)[2 * i];
        flt4 b = ((const flt4*)in)[2 * i + 1];
        ushort8 o;
        o[0] = f2bf(a[0]); o[1] = f2bf(a[1]); o[2] = f2bf(a[2]); o[3] = f2bf(a[3]);
        o[4] = f2bf(b[0]); o[5] = f2bf(b[1]); o[6] = f2bf(b[2]); o[7] = f2bf(b[3]);
        ((ushort8*)out)[i] = o;
    }
}

__global__ __launch_bounds__(256) void convert_vt_u_kernel(
    const float* __restrict__ vt_f, ushort* __restrict__ vt_b, long nVT8,
    const float* __restrict__ u_f,  ushort* __restrict__ u_b,  long nU8)
{
    const int b = blockIdx.x;
    if (b < 896) conv_seg(vt_f, vt_b, nVT8, b,       896);
    else         conv_seg(u_f,  u_b,  nU8,  b - 896, 128);
}

// ---- store helpers ----
__device__ __forceinline__ void store_out(ushort* p, float v) { *p = f2bf(v); }
__device__ __forceinline__ void store_out(float*  p, float v) { *p = v; }

// =====================================================================
// GEMM1: latent[16384 x 2048] = hidden_f32[16384 x 4096] * VT_bf16^T
// 4-wave 128x128, T2 swizzle, single A bank, extended B shadow.
// =====================================================================
__global__ __launch_bounds__(256) void gemm1_fused_kernel(
    const float* __restrict__ Af,
    const ushort* __restrict__ B,
    ushort* __restrict__ C,
    int lda, int ldb, int ldc, int K, int bxShift)
{
    __shared__ ushort As[128 * 64];      // 16 KiB (single, swizzled)
    __shared__ ushort Bs[2][128 * 64];   // 32 KiB (double, swizzled via src)

    const int tid  = threadIdx.x;
    const int lane = tid & 63;
    const int wave = tid >> 6;

    const int bid = blockIdx.x;
    const int xcd = bid & 7;
    const int rr  = bid >> 3;
    const int by  = xcd * 16 + (rr >> bxShift);
    const int bx  = rr & ((1 << bxShift) - 1);

    const int row0 = by * 128;
    const int col0 = bx * 128;

    const int wr = wave >> 1;
    const int wc = wave & 1;

    const int l15    = lane & 15;
    const int lq     = lane >> 4;
    const int lrow   = lane >> 3;
    const int lchunk = lane & 7;
    const int l7     = lane & 7;

    f32x4 acc[4][4] = {};
    flt4 pa[8];                      // A data in flight (32 VGPR)

    const float*  aF   = Af + (size_t)(row0 + wave * 32 + lrow) * lda + lchunk * 8;
    const ushort* bPtr = B  + (size_t)(col0 + wave * 32 + lrow) * ldb
                            + ((lchunk ^ lrow) * 8);
    ushort* aDstBase = As + wave * 4 * 512 + lrow * 64 + ((lchunk ^ lrow) * 8);

    const int nkt = K / 64;

    // prologue: load A(0) into regs, issue B(0) -> Bs[0]
    #pragma unroll
    for (int i = 0; i < 4; ++i) {
        const float* s = aF + (size_t)(i * 8) * lda;
        pa[2*i] = *(const flt4*)(s);  pa[2*i+1] = *(const flt4*)(s + 4);
    }
    #pragma unroll
    for (int i = 0; i < 4; ++i)
        gload_lds16(bPtr + (size_t)i * 8 * ldb, Bs[0] + (wave * 4 + i) * 512);

    for (int kt = 0; kt < nkt; ++kt) {
        __syncthreads();   // barrier_A (full drain): pa(kt) + B(kt) resident

        // cvt + ds_write A(kt) (swizzled slot)
        #pragma unroll
        for (int i = 0; i < 4; ++i) {
            uint4 w;
            w.x = cvtpk(pa[2*i][0],   pa[2*i][1]);
            w.y = cvtpk(pa[2*i][2],   pa[2*i][3]);
            w.z = cvtpk(pa[2*i+1][0], pa[2*i+1][1]);
            w.w = cvtpk(pa[2*i+1][2], pa[2*i+1][3]);
            *(uint4*)(aDstBase + i * 512) = w;
        }
        // issue B(kt+1) now: its buffer's readers finished before barrier_A,
        // and the raw barrier below does NOT drain it (extended shadow).
        if (kt + 1 < nkt) {
            const int kN = (kt + 1) * 64;
            #pragma unroll
            for (int i = 0; i < 4; ++i)
                gload_lds16(bPtr + (size_t)i * 8 * ldb + kN,
                            Bs[(kt + 1) & 1] + (wave * 4 + i) * 512);
        }
        // barrier_B: LDS-ordering only (ds_writes of A visible); B in flight
        asm volatile("s_waitcnt lgkmcnt(0)" ::: "memory");
        __builtin_amdgcn_s_barrier();

        // reload pa with A(kt+1) (regs freed by cvt; flies across MFMAs)
        if (kt + 1 < nkt) {
            const int kN = (kt + 1) * 64;
            #pragma unroll
            for (int i = 0; i < 4; ++i) {
                const float* s = aF + (size_t)(i * 8) * lda + kN;
                pa[2*i] = *(const flt4*)(s);  pa[2*i+1] = *(const flt4*)(s + 4);
            }
        }

        // MFMA tile kt (swizzled reads)
        const ushort* bCur = Bs[kt & 1];
        #pragma unroll
        for (int kk = 0; kk < 2; ++kk) {
            const int rc = ((((kk << 2) | lq) ^ l7) << 3);
            bf16x8 af[4], bfr[4];
            #pragma unroll
            for (int m = 0; m < 4; ++m)
                af[m] = *(const bf16x8*)&As[(wr * 64 + m * 16 + l15) * 64 + rc];
            #pragma unroll
            for (int n = 0; n < 4; ++n)
                bfr[n] = *(const bf16x8*)&bCur[(wc * 64 + n * 16 + l15) * 64 + rc];
            #pragma unroll
            for (int m = 0; m < 4; ++m)
                #pragma unroll
                for (int n = 0; n < 4; ++n)
                    acc[m][n] = __builtin_amdgcn_mfma_f32_16x16x32_bf16(
                        af[m], bfr[n], acc[m][n], 0, 0, 0);
        }
    }

    // C/D layout: col = lane&15, row = (lane>>4)*4 + reg
    #pragma unroll
    for (int m = 0; m < 4; ++m) {
        #pragma unroll
        for (int r = 0; r < 4; ++r) {
            const size_t row = (size_t)(row0 + wr * 64 + m * 16 + lq * 4 + r);
            ushort* cRow = C + row * ldc + col0 + wc * 64 + l15;
            #pragma unroll
            for (int n = 0; n < 4; ++n)
                cRow[n * 16] = f2bf(acc[m][n][r]);
        }
    }
}

// =====================================================================
// GEMM2 (8-wave, T2 swizzle -- r18 verbatim): block-diagonal
// out[:, g*512:+512] = latent[:, g*256:+256] * U[g]^T, f32 out.
// =====================================================================
template <typename TOUT>
__global__ __launch_bounds__(512) void gemm_bt8_kernel(
    const ushort* __restrict__ A,
    const ushort* __restrict__ B,
    TOUT* __restrict__ C,
    int lda, int ldb, int ldc, int K, int bxShift,
    long aOffZ, long bOffZ, long cOffZ)
{
    A += (size_t)blockIdx.z * aOffZ;
    B += (size_t)blockIdx.z * bOffZ;
    C += (size_t)blockIdx.z * cOffZ;

    __shared__ ushort As[128 * 64];
    __shared__ ushort Bs[128 * 64];

    const int tid  = threadIdx.x;
    const int lane = tid & 63;
    const int wave = tid >> 6;       // 0..7

    const int bid = blockIdx.x;
    const int xcd = bid & 7;
    const int rr  = bid >> 3;
    const int by  = xcd * 16 + (rr >> bxShift);
    const int bx  = rr & ((1 << bxShift) - 1);

    const int row0 = by * 128;
    const int col0 = bx * 128;

    const int wr = wave >> 2;        // 0..1
    const int wc = wave & 3;         // 0..3

    const int l15    = lane & 15;
    const int lq     = lane >> 4;
    const int lrow   = lane >> 3;
    const int lchunk = lane & 7;
    const int l7     = lane & 7;

    f32x4 acc[4][2] = {};

    const ushort* aPtr = A + (size_t)(row0 + wave * 8 + lrow) * lda
                           + ((lchunk ^ lrow) * 8);
    const ushort* bPtr = B + (size_t)(col0 + wave * 8 + lrow) * ldb
                           + ((lchunk ^ lrow) * 8);
    const int ldsseg = wave * 512;

    const int nkt = K / 64;
    for (int kt = 0; kt < nkt; ++kt) {
        const int kOff = kt * 64;
        __syncthreads();
        #pragma unroll
        for (int i = 0; i < 2; ++i) {
            gload_lds16(aPtr + (size_t)i * 64 * lda + kOff, As + i * 4096 + ldsseg);
            gload_lds16(bPtr + (size_t)i * 64 * ldb + kOff, Bs + i * 4096 + ldsseg);
        }
        __syncthreads();

        #pragma unroll
        for (int kk = 0; kk < 2; ++kk) {
            const int rc = ((((kk << 2) | lq) ^ l7) << 3);
            bf16x8 af[4], bfr[2];
            #pragma unroll
            for (int m = 0; m < 4; ++m)
                af[m] = *(const bf16x8*)&As[(wr * 64 + m * 16 + l15) * 64 + rc];
            #pragma unroll
            for (int n = 0; n < 2; ++n)
                bfr[n] = *(const bf16x8*)&Bs[(wc * 32 + n * 16 + l15) * 64 + rc];
            #pragma unroll
            for (int m = 0; m < 4; ++m)
                #pragma unroll
                for (int n = 0; n < 2; ++n)
                    acc[m][n] = __builtin_amdgcn_mfma_f32_16x16x32_bf16(
                        af[m], bfr[n], acc[m][n], 0, 0, 0);
        }
    }

    #pragma unroll
    for (int m = 0; m < 4; ++m) {
        #pragma unroll
        for (int r = 0; r < 4; ++r) {
            const size_t row = (size_t)(row0 + wr * 64 + m * 16 + lq * 4 + r);
            TOUT* cRow = C + row * ldc + col0 + wc * 32 + l15;
            #pragma unroll
            for (int n = 0; n < 2; ++n)
                store_out(cRow + n * 16, acc[m][n][r]);
        }
    }
}

extern "C" void kernel_launch(void* const* d_in, const int* in_sizes, int n_in,
                              void* d_out, int out_size, void* d_ws, size_t ws_size,
                              hipStream_t stream) {
    const float* hidden_f = (const float*)d_in[0];  // 16384 x 4096 f32
    const float* VT_f     = (const float*)d_in[1];  // 2048 x 4096 f32 (N,K)
    const float* U_f      = (const float*)d_in[2];  // 8 x 512 x 256 f32
    float* out = (float*)d_out;                     // 16384 x 4096 f32

    const long nVT  = 2048L * 4096L;
    const long nU   = 8L * 512L * 256L;
    const long nLat = 16384L * 2048L;

    // lat_b and u_b MUST live in ws (GEMM2 reads them while writing d_out).
    // vt_b may fall back into d_out (read only by GEMM1, which writes ws).
    ushort *vt_b, *u_b, *lat_b;
    const size_t needA = (size_t)(nVT + nU + nLat) * 2;   // ~86 MB
    ushort* w = (ushort*)d_ws;
    lat_b = w;  u_b = lat_b + nLat;
    if (ws_size >= needA) vt_b = u_b + nU;
    else                  vt_b = (ushort*)d_out;          // staged in d_out

    // convert VT + U (~100 MB traffic)
    convert_vt_u_kernel<<<dim3(1024), dim3(256), 0, stream>>>(
        VT_f, vt_b, nVT / 8, U_f, u_b, nU / 8);

    // GEMM1: latent = hidden_f32 * VT^T (fused, T2 swizzle, extended B shadow)
    gemm1_fused_kernel<<<dim3(2048, 1, 1), dim3(256), 0, stream>>>(
        hidden_f, vt_b, lat_b, 4096, 4096, 2048, 4096, 4);

    // GEMM2 (block-diag, 8-wave, T2 swizzle)
    gemm_bt8_kernel<float><<<dim3(512, 1, 8), dim3(512), 0, stream>>>(
        lat_b, u_b, out, 2048, 256, 4096, 256, 2,
        256L, 512L * 256L, 512L);
}